// Round 7
// baseline (170.314 us; speedup 1.0000x reference)
//
#include <hip/hip_runtime.h>

#define N_TOK 131072
#define TILE 32              // tokens per block (one tile per block)
#define NT_MAX 4112          // N_TOK/TILE + 16 tasks worth of padding tiles

typedef __attribute__((ext_vector_type(8))) short s8v;
typedef __attribute__((ext_vector_type(4))) float f4v;
typedef unsigned short ushort_t;

__device__ __forceinline__ unsigned short f2bf(float x) {
    union { float f; unsigned u; } v; v.f = x;
    unsigned r = v.u + 0x7fffu + ((v.u >> 16) & 1u);   // RNE (prep only)
    return (unsigned short)(r >> 16);
}

// round-half-up pack of two f32 -> packed bf16x2 via v_perm_b32 (3 VALU ops)
__device__ __forceinline__ unsigned pk2(float a, float b) {
    union { float f; unsigned u; } x, y; x.f = a; y.f = b;
    return __byte_perm(x.u + 0x8000u, y.u + 0x8000u, 0x7632);
}

// tanh = 1 - 2/(e^2x+1); e^2x = exp2(x * 2*log2(e)): mul, exp2, add, rcp, fma
__device__ __forceinline__ float tanh_fast(float x) {
    float e = __builtin_amdgcn_exp2f(x * 2.8853900817779268f);
    float r = __builtin_amdgcn_rcpf(e + 1.0f);
    return __builtin_fmaf(-2.0f, r, 1.0f);
}

// ------------------------------------------------- fused prep + hist
__global__ void prep_hist_kernel(const float* __restrict__ W0, const float* __restrict__ W1,
                                 const float* __restrict__ W2,
                                 ushort_t* __restrict__ W0p, ushort_t* __restrict__ W1p,
                                 ushort_t* __restrict__ W2p,
                                 const int* __restrict__ task, int* __restrict__ blockCounts) {
    if (blockIdx.x < 224) {
        int f = blockIdx.x * 256 + threadIdx.x;   // 57344 total fragments
        const float* src; ushort_t* dst; int K, N;
        if (f < 16384)      { src = W0; dst = W0p; K = 128; N = 256; }
        else if (f < 49152) { src = W1; dst = W1p; K = 256; N = 256; f -= 16384; }
        else                { src = W2; dst = W2p; K = 256; N = 64;  f -= 49152; }
        int fpc = (N >> 4) * (K >> 5) * 64;       // fragments per copy
        int c = f / fpc, r = f % fpc;
        int lane = r & 63;
        int kt = (r >> 6) % (K >> 5);
        int ftile = (r >> 6) / (K >> 5);
        int n = ftile * 16 + (lane & 15);
        int kbase = kt * 32 + (lane >> 4) * 8;
        const float* s = src + (size_t)c * K * N + (size_t)kbase * N + n;
        s8v pk;
#pragma unroll
        for (int j = 0; j < 8; j++) pk[j] = (short)f2bf(s[(size_t)j * N]);
        *reinterpret_cast<s8v*>(dst + ((size_t)(c * fpc + r) << 3)) = pk;
    } else {
        __shared__ int cnt[16];
        int t = threadIdx.x;
        int hb = blockIdx.x - 224;
        if (t < 16) cnt[t] = 0;
        __syncthreads();
        int base = hb * 2048 + t;
#pragma unroll
        for (int i = 0; i < 8; i++) atomicAdd(&cnt[task[base + i * 256]], 1);
        __syncthreads();
        if (t < 16) blockCounts[hb * 16 + t] = cnt[t];
    }
}

// ------------------------------------------------- fused scan + scatter
__global__ void sort_kernel(const int* __restrict__ task, const int* __restrict__ blockCounts,
                            int* __restrict__ tileTask, int* __restrict__ nT,
                            int* __restrict__ perm) {
    __shared__ int cntLds[1024];
    __shared__ int total[16], pref[16], rank[16];
    __shared__ int tokBase[16], tbase[17];
    int t = threadIdx.x, b = blockIdx.x;
    for (int i = t; i < 1024; i += 256) cntLds[i] = blockCounts[i];
    if (t < 16) rank[t] = 0;
    __syncthreads();
    if (t < 16) {
        int tot = 0, pf = 0;
#pragma unroll
        for (int bb = 0; bb < 64; bb++) {
            int v = cntLds[bb * 16 + t];
            tot += v;
            if (bb < b) pf += v;
        }
        total[t] = tot; pref[t] = pf;
    }
    __syncthreads();
    if (t == 0) {
        int tok = 0, tile = 0;
        for (int k = 0; k < 16; k++) {
            tokBase[k] = tok;
            tbase[k] = tile;
            int ntk = (total[k] + TILE - 1) / TILE;
            tok += ntk * TILE;
            tile += ntk;
        }
        tbase[16] = tile;
        if (b == 0) nT[0] = tile;
    }
    __syncthreads();
    if (b == 0) {
        for (int i = t; i < NT_MAX; i += 256) {
            int tk = 0;
            if (i < tbase[16]) {
#pragma unroll
                for (int k = 0; k < 16; k++) if (i >= tbase[k]) tk = k;
            }
            tileTask[i] = tk;
        }
        // fill padding slots with -1 (don't rely on ws poison being >= N_TOK)
        for (int i = t; i < 16 * TILE; i += 256) {
            int k = i >> 5, off = i & (TILE - 1);
            int idx = total[k] + off;
            int lim = ((total[k] + TILE - 1) / TILE) * TILE;
            if (idx < lim) perm[tokBase[k] + idx] = -1;
        }
    }
    int tk[8], my[8];
#pragma unroll
    for (int i = 0; i < 8; i++) {
        int idx = b * 2048 + i * 256 + t;
        tk[i] = task[idx];
        my[i] = atomicAdd(&rank[tk[i]], 1);
    }
#pragma unroll
    for (int i = 0; i < 8; i++) {
        int idx = b * 2048 + i * 256 + t;
        perm[tokBase[tk[i]] + pref[tk[i]] + my[i]] = idx;
    }
}

// ------------------------------------------------- fused MLP, pipelined loads
// Round-6 postmortem: VGPR=44 proved the compiler issues every weight load
// just-before-use -> ~20 exposed ~250cy L2 chains per tile ~= the whole 10K
// cy/tile plateau (invariant across occupancy 18-72%). Fix: issue load
// CLUSTERS at phase starts, pinned with sched_barrier(0) so the scheduler
// can't sink them: L0 weights before the stage barrier (hide under gather),
// L1 first-half weights under L0's tanh epilogue, L2 weights + out-tokens
// under L1's epilogue; ds_reads issued as one cluster per half-layer before
// the MFMA cluster. Live set by construction ~105-125 VGPR (L1 kt-halved).
__launch_bounds__(512, 3)
__global__ void mlp_kernel(const float* __restrict__ x_in,
                           const int* __restrict__ cmap,
                           const float* __restrict__ b0,
                           const float* __restrict__ b1,
                           const float* __restrict__ b2,
                           const ushort_t* __restrict__ W0p,
                           const ushort_t* __restrict__ W1p,
                           const ushort_t* __restrict__ W2p,
                           const int* __restrict__ tileTask,
                           const int* __restrict__ nTp,
                           const int* __restrict__ perm,
                           float* __restrict__ out) {
    __shared__ __align__(16) ushort_t H1[8192];    // 2 tt * 8 kt * 64 * 8 = 16 KB
    __shared__ __align__(16) ushort_t XH2[8192];   // X: frags [0,8) (8 KB); H2: frags [0,16)

    int b = blockIdx.x;
    if (b >= nTp[0]) return;
    int t = threadIdx.x;
    int task = tileTask[b];
    int c0 = cmap[task], c1 = cmap[16 + task], c2 = cmap[32 + task];

    int w = t >> 6;                 // wave 0..7
    int lane = t & 63;
    int l15 = lane & 15, lq = lane >> 4;
    int mt2 = w & 3, nt2 = w >> 2;  // layer-2 tile assignment

    const ushort_t* Wc0 = W0p + (size_t)c0 * 32768;
    const ushort_t* Wc1 = W1p + (size_t)c1 * 65536;
    const ushort_t* Wc2 = W2p + (size_t)c2 * 16384;

    // ======== initial issue cluster: stage-perm, L0 weights, biases, out-tokens
    int rS = t >> 4, qS = t & 15;          // staging coords: token rS, k = qS*8..qS*8+7
    int tokS = perm[b * TILE + rS];
    s8v wa0[2][4];
#pragma unroll
    for (int mi = 0; mi < 2; mi++)
#pragma unroll
        for (int kt = 0; kt < 4; kt++)
            wa0[mi][kt] = *reinterpret_cast<const s8v*>(Wc0 + ((((2 * w + mi) * 4 + kt) * 64 + lane) << 3));
    f4v bv0[2], bv1[2], bv2;
#pragma unroll
    for (int mi = 0; mi < 2; mi++) {
        bv0[mi] = *reinterpret_cast<const f4v*>(b0 + c0 * 256 + (2 * w + mi) * 16 + lq * 4);
        bv1[mi] = *reinterpret_cast<const f4v*>(b1 + c1 * 256 + (2 * w + mi) * 16 + lq * 4);
    }
    bv2 = *reinterpret_cast<const f4v*>(b2 + c2 * 64 + mt2 * 16 + lq * 4);
    int tokO = perm[b * TILE + nt2 * 16 + l15];   // this wave's output tokens (L2)
    __builtin_amdgcn_sched_barrier(0);

    // ======== stage X: gather + cvt into B-fragment order (one uint4/thread)
    {
        float4 v0 = make_float4(0.f, 0.f, 0.f, 0.f), v1 = v0;
        if ((unsigned)tokS < (unsigned)N_TOK) {
            const float4* src = reinterpret_cast<const float4*>(x_in) + (size_t)tokS * 32 + qS * 2;
            v0 = src[0]; v1 = src[1];
        }
        int fragid = (rS >> 4) * 4 + (qS >> 2);
        int lanep = (rS & 15) + 16 * (qS & 3);
        uint4 pk;
        pk.x = pk2(v0.x, v0.y); pk.y = pk2(v0.z, v0.w);
        pk.z = pk2(v1.x, v1.y); pk.w = pk2(v1.z, v1.w);
        *reinterpret_cast<uint4*>(&XH2[(fragid * 64 + lanep) << 3]) = pk;
    }
    __syncthreads();

    // ======== Layer 0: H1^T = W0^T X^T. Wave w: ftiles {2w,2w+1} x 2 token tiles.
    s8v wa1a[2][4];   // L1 first-half weights, issued during L0 epilogue
    {
        // ds cluster: all 8 xb frags
        s8v xb[2][4];
#pragma unroll
        for (int nt = 0; nt < 2; nt++)
#pragma unroll
            for (int kt = 0; kt < 4; kt++)
                xb[nt][kt] = *reinterpret_cast<const s8v*>(&XH2[((nt * 4 + kt) * 64 + lane) << 3]);
        __builtin_amdgcn_sched_barrier(0);
        f4v acc[2][2];
#pragma unroll
        for (int mi = 0; mi < 2; mi++) { acc[mi][0] = bv0[mi]; acc[mi][1] = bv0[mi]; }
#pragma unroll
        for (int kt = 0; kt < 4; kt++)
#pragma unroll
            for (int mi = 0; mi < 2; mi++)
#pragma unroll
                for (int nt = 0; nt < 2; nt++)
                    acc[mi][nt] = __builtin_amdgcn_mfma_f32_16x16x32_bf16(wa0[mi][kt], xb[nt][kt], acc[mi][nt], 0, 0, 0);
        // issue L1 first-half weight loads; tanh epilogue (~350cy VALU) hides them
#pragma unroll
        for (int mi = 0; mi < 2; mi++)
#pragma unroll
            for (int kt = 0; kt < 4; kt++)
                wa1a[mi][kt] = *reinterpret_cast<const s8v*>(Wc1 + ((((2 * w + mi) * 8 + kt) * 64 + lane) << 3));
        __builtin_amdgcn_sched_barrier(0);
#pragma unroll
        for (int mi = 0; mi < 2; mi++) {
            int ft = 2 * w + mi;
            int kt_h = ft >> 1;
            int lanep = l15 + 16 * ((ft & 1) * 2 + (lq >> 1));
            int j0 = (lq & 1) * 4;
#pragma unroll
            for (int nt = 0; nt < 2; nt++) {
                float t0 = tanh_fast(acc[mi][nt][0]);
                float t1 = tanh_fast(acc[mi][nt][1]);
                float t2 = tanh_fast(acc[mi][nt][2]);
                float t3 = tanh_fast(acc[mi][nt][3]);
                uint2 pk; pk.x = pk2(t0, t1); pk.y = pk2(t2, t3);
                *reinterpret_cast<uint2*>(&H1[(((nt * 8 + kt_h) * 64 + lanep) << 3) + j0]) = pk;
            }
        }
    }
    __syncthreads();

    // ======== Layer 1: H2^T = W1^T H1^T, kt-halved pipeline. (H2 overlays X.)
    s8v wa2[8];       // L2 weights, issued during L1 epilogue
    {
        f4v acc[2][2];
#pragma unroll
        for (int mi = 0; mi < 2; mi++) { acc[mi][0] = bv1[mi]; acc[mi][1] = bv1[mi]; }
        // half A: ds cluster kt 0..3
        s8v xba[2][4];
#pragma unroll
        for (int nt = 0; nt < 2; nt++)
#pragma unroll
            for (int kt = 0; kt < 4; kt++)
                xba[nt][kt] = *reinterpret_cast<const s8v*>(&H1[((nt * 8 + kt) * 64 + lane) << 3]);
        __builtin_amdgcn_sched_barrier(0);
#pragma unroll
        for (int kt = 0; kt < 4; kt++)
#pragma unroll
            for (int mi = 0; mi < 2; mi++)
#pragma unroll
                for (int nt = 0; nt < 2; nt++)
                    acc[mi][nt] = __builtin_amdgcn_mfma_f32_16x16x32_bf16(wa1a[mi][kt], xba[nt][kt], acc[mi][nt], 0, 0, 0);
        // half B: weights kt 4..7 + ds cluster kt 4..7
        s8v wa1b[2][4], xbb[2][4];
#pragma unroll
        for (int mi = 0; mi < 2; mi++)
#pragma unroll
            for (int kt = 0; kt < 4; kt++)
                wa1b[mi][kt] = *reinterpret_cast<const s8v*>(Wc1 + ((((2 * w + mi) * 8 + kt + 4) * 64 + lane) << 3));
#pragma unroll
        for (int nt = 0; nt < 2; nt++)
#pragma unroll
            for (int kt = 0; kt < 4; kt++)
                xbb[nt][kt] = *reinterpret_cast<const s8v*>(&H1[((nt * 8 + kt + 4) * 64 + lane) << 3]);
        __builtin_amdgcn_sched_barrier(0);
#pragma unroll
        for (int kt = 0; kt < 4; kt++)
#pragma unroll
            for (int mi = 0; mi < 2; mi++)
#pragma unroll
                for (int nt = 0; nt < 2; nt++)
                    acc[mi][nt] = __builtin_amdgcn_mfma_f32_16x16x32_bf16(wa1b[mi][kt], xbb[nt][kt], acc[mi][nt], 0, 0, 0);
        // issue L2 weights; tanh epilogue hides them
#pragma unroll
        for (int kt = 0; kt < 8; kt++)
            wa2[kt] = *reinterpret_cast<const s8v*>(Wc2 + (((mt2 * 8 + kt) * 64 + lane) << 3));
        __builtin_amdgcn_sched_barrier(0);
#pragma unroll
        for (int mi = 0; mi < 2; mi++) {
            int ft = 2 * w + mi;
            int kt_h = ft >> 1;
            int lanep = l15 + 16 * ((ft & 1) * 2 + (lq >> 1));
            int j0 = (lq & 1) * 4;
#pragma unroll
            for (int nt = 0; nt < 2; nt++) {
                float t0 = tanh_fast(acc[mi][nt][0]);
                float t1 = tanh_fast(acc[mi][nt][1]);
                float t2 = tanh_fast(acc[mi][nt][2]);
                float t3 = tanh_fast(acc[mi][nt][3]);
                uint2 pk; pk.x = pk2(t0, t1); pk.y = pk2(t2, t3);
                *reinterpret_cast<uint2*>(&XH2[(((nt * 8 + kt_h) * 64 + lanep) << 3) + j0]) = pk;
            }
        }
    }
    __syncthreads();

    // ======== Layer 2: O^T = W2^T H2^T. 4 mt x 2 nt tiles / 8 waves = 1/wave.
    {
        s8v xb[8];
#pragma unroll
        for (int kt = 0; kt < 8; kt++)
            xb[kt] = *reinterpret_cast<const s8v*>(&XH2[((nt2 * 8 + kt) * 64 + lane) << 3]);
        __builtin_amdgcn_sched_barrier(0);
        f4v acc = bv2;
#pragma unroll
        for (int kt = 0; kt < 8; kt++)
            acc = __builtin_amdgcn_mfma_f32_16x16x32_bf16(wa2[kt], xb[kt], acc, 0, 0, 0);
        if ((unsigned)tokO < (unsigned)N_TOK) {
            float4 o;
            o.x = acc[0]; o.y = acc[1]; o.z = acc[2]; o.w = acc[3];
            *reinterpret_cast<float4*>(out + (size_t)tokO * 64 + mt2 * 16 + lq * 4) = o;
        }
    }
}

// ---------------------------------------------------------------- launch
extern "C" void kernel_launch(void* const* d_in, const int* in_sizes, int n_in,
                              void* d_out, int out_size, void* d_ws, size_t ws_size,
                              hipStream_t stream) {
    const float* inputs = (const float*)d_in[0];
    const int*   task   = (const int*)d_in[1];
    const int*   cmap   = (const int*)d_in[2];
    const float* W0     = (const float*)d_in[3];
    const float* b0     = (const float*)d_in[4];
    const float* W1     = (const float*)d_in[5];
    const float* b1     = (const float*)d_in[6];
    const float* W2     = (const float*)d_in[7];
    const float* b2     = (const float*)d_in[8];
    float* out = (float*)d_out;

    char* ws = (char*)d_ws;
    int* blockCounts = (int*)(ws + 0);            // 64*16*4 = 4096 B
    int* nT          = (int*)(ws + 4096);         // 4 B (pad to 64)
    int* tileTask    = (int*)(ws + 4160);         // 4112*4 = 16448 B -> ends 20608
    int* perm        = (int*)(ws + 20608);        // 4112*32*4 = 526336 B -> ends 546944
    ushort_t* W0p    = (ushort_t*)(ws + 546944);  // 262144 B
    ushort_t* W1p    = (ushort_t*)(ws + 809088);  // 524288 B
    ushort_t* W2p    = (ushort_t*)(ws + 1333376); // 131072 B -> total ~1.40 MB

    prep_hist_kernel<<<288, 256, 0, stream>>>(W0, W1, W2, W0p, W1p, W2p, task, blockCounts);
    sort_kernel<<<64, 256, 0, stream>>>(task, blockCounts, tileTask, nT, perm);
    mlp_kernel<<<NT_MAX, 512, 0, stream>>>(inputs, cmap, b0, b1, b2,
                                           W0p, W1p, W2p, tileTask, nT, perm, out);
}